// Round 2
// baseline (601.939 us; speedup 1.0000x reference)
//
#include <hip/hip_runtime.h>
#include <hip/hip_bf16.h>

// GraphLayer B=8,N=2048,D=512 — Round 6.
//   r5 post-mortem: fused attn = 342us but MfmaUtil 8%, Occ 23%, FETCH 599MB.
//   Cause 1: grid 256 = 1 block/CU -> ~416 full-CU barrier drains/block.
//   Cause 2: K/V re-fetched per k-tile; no XCD locality -> 3.3x overfetch.
//   Changes:
//   1) K and V fragments read DIRECTLY from global (no LDS staging): per-batch
//      K/V slabs are 2MB each -> fit one XCD's 4MB L2. Phase 1 and phase 2
//      have ZERO staging barriers; only 1 barrier per k-tile (P handoff,
//      double-buffered).
//   2) QB 64->32: grid 512 = 2 blocks/CU (LDS 48.5KB, VGPR<=128) so barriers
//      overlap with the co-resident block.
//   3) XCD-affinity: b = linear_block_id % 8 -> all blocks of batch b on XCD b
//      (round-robin dispatch) -> K/V hit that XCD's L2 after first fetch.
//   4) adj loads / out stores nontemporal: 134MB adj stream doesn't evict K/V.
//   5) Q tile persistent in LDS (loaded once, XOR-granule swizzled source).
// Numerics unchanged vs r4/r5 (absmax 0.0156): fp16 Q/K path, P/V bf16,
// fp32 accum, den = fp32 sum of the SAME bf16-rounded P (cancellation kept).

#define BATCH 8
#define SEQ   2048
#define DIM   512
#define MSEQ  (BATCH * SEQ)   // 16384
#define QB    32              // q-rows per attn block
#define KT    128             // k-tile width

typedef __attribute__((ext_vector_type(8))) short    bf16x8;
typedef __attribute__((ext_vector_type(8))) _Float16 f16x8;
typedef __attribute__((ext_vector_type(4))) float    f32x4;

__device__ __forceinline__ unsigned short f2bf(float f) {
  __hip_bfloat16 h = __float2bfloat16(f);
  union { __hip_bfloat16 h; unsigned short u; } c; c.h = h; return c.u;
}
__device__ __forceinline__ float bf2f(unsigned short u) {
  union { unsigned int u; float f; } c; c.u = ((unsigned int)u) << 16; return c.f;
}
__device__ __forceinline__ unsigned short f2h(float f) {
  union { _Float16 h; unsigned short u; } c; c.h = (_Float16)f; return c.u;
}

__device__ __forceinline__ void async16(const unsigned short* g, unsigned short* l) {
  __builtin_amdgcn_global_load_lds(
      (const __attribute__((address_space(1))) void*)g,
      (__attribute__((address_space(3))) void*)l, 16, 0, 0);
}

// ---------------------------------------------------------------- core ----
// acc[i][j] += A[m][k] * B[n][k]  (NT), fp16 MFMA, fp32 acc. 256 threads.
// LDS rows 32 ushorts (64B, 4 granules); XOR-swizzled granules (2-way banks).
__device__ __forceinline__ void gemm_f16_mainloop(
    const unsigned short* __restrict__ A, const unsigned short* __restrict__ B,
    int lda, int ldb, int K,
    unsigned short* sA, unsigned short* sB, f32x4 acc[4][4])
{
  const int tid  = threadIdx.x;
  const int lane = tid & 63;
  const int w    = tid >> 6;
  const int wm   = w >> 1, wn = w & 1;
  const int quad = lane >> 4, fcol = lane & 15;
  const int srow = lane >> 2;          // 0..15 within a 16-row chunk
  const int gsw  = ((lane & 3) ^ ((srow & 3) ^ ((srow >> 2) & 3))) * 8;
  const int grd  = ((fcol & 3) ^ ((fcol >> 2) & 3));

  for (int k0 = 0; k0 < K; k0 += 32) {
#pragma unroll
    for (int inst = 0; inst < 2; ++inst) {
      const int rbase  = w * 32 + inst * 16;   // wave-uniform
      const int r      = rbase + srow;
      const int ldsoff = rbase * 32;           // row stride 32 ushorts
      async16(A + (size_t)r * lda + k0 + gsw, sA + ldsoff);
      async16(B + (size_t)r * ldb + k0 + gsw, sB + ldsoff);
    }
    __syncthreads();

#pragma unroll
    for (int i = 0; i < 4; ++i) {
      const int ar = wm * 64 + i * 16 + fcol;
      f16x8 a = *(const f16x8*)(sA + ar * 32 + ((quad ^ grd) << 3));
#pragma unroll
      for (int j = 0; j < 4; ++j) {
        const int br = wn * 64 + j * 16 + fcol;
        f16x8 b = *(const f16x8*)(sB + br * 32 + ((quad ^ grd) << 3));
        acc[i][j] = __builtin_amdgcn_mfma_f32_16x16x32_f16(a, b, acc[i][j], 0, 0, 0);
      }
    }
    __syncthreads();
  }
}

#define EPI_SETUP                                                  \
  const int lane = threadIdx.x & 63;                               \
  const int w_   = threadIdx.x >> 6;                               \
  const int wm   = w_ >> 1, wn = w_ & 1;                           \
  const int quad = lane >> 4, fcol = lane & 15;

// ----------------------------------------------------------------- cvt ----
__global__ __launch_bounds__(256) void cvt_kernel(
    const float* __restrict__ in, unsigned short* __restrict__ out, int n4)
{
  int i = blockIdx.x * 256 + threadIdx.x;
  if (i >= n4) return;
  float4 v = ((const float4*)in)[i];
  ushort4 h;
  h.x = f2h(v.x); h.y = f2h(v.y); h.z = f2h(v.z); h.w = f2h(v.w);
  ((ushort4*)out)[i] = h;
}

__global__ __launch_bounds__(256) void cvt_w_kernel(
    const float* __restrict__ w0, const float* __restrict__ w1,
    const float* __restrict__ w2, unsigned short* __restrict__ o0,
    unsigned short* __restrict__ o1, unsigned short* __restrict__ o2, int n4)
{
  int i = blockIdx.x * 256 + threadIdx.x;
  if (i >= n4) return;
  const float* in = (blockIdx.y == 0) ? w0 : (blockIdx.y == 1) ? w1 : w2;
  unsigned short* out = (blockIdx.y == 0) ? o0 : (blockIdx.y == 1) ? o1 : o2;
  float4 v = ((const float4*)in)[i];
  ushort4 h;
  h.x = f2h(v.x); h.y = f2h(v.y); h.z = f2h(v.z); h.w = f2h(v.w);
  ((ushort4*)out)[i] = h;
}

// ------------------------------------------------------------- proj QK ----
__global__ __launch_bounds__(256) void proj_qk_kernel(
    const unsigned short* __restrict__ xh,
    const unsigned short* __restrict__ wq, const unsigned short* __restrict__ wk,
    const float* __restrict__ bq, const float* __restrict__ bk,
    unsigned short* __restrict__ Qh, unsigned short* __restrict__ Kh)
{
  __shared__ unsigned short sA[128 * 32], sB[128 * 32];
  const unsigned short* wh = blockIdx.z ? wk : wq;
  const float* bias        = blockIdx.z ? bk : bq;
  unsigned short* O        = blockIdx.z ? Kh : Qh;
  const int m0 = blockIdx.y * 128, n0 = blockIdx.x * 128;
  f32x4 acc[4][4];
#pragma unroll
  for (int i = 0; i < 4; ++i)
#pragma unroll
    for (int j = 0; j < 4; ++j) acc[i][j] = (f32x4){0.f, 0.f, 0.f, 0.f};

  gemm_f16_mainloop(xh + (size_t)m0 * DIM, wh + (size_t)n0 * DIM,
                    DIM, DIM, DIM, sA, sB, acc);
  EPI_SETUP
#pragma unroll
  for (int i = 0; i < 4; ++i)
#pragma unroll
    for (int j = 0; j < 4; ++j)
#pragma unroll
      for (int r = 0; r < 4; ++r) {
        const int row = m0 + wm * 64 + i * 16 + quad * 4 + r;
        const int col = n0 + wn * 64 + j * 16 + fcol;
        O[(size_t)row * DIM + col] = f2h(acc[i][j][r] + bias[col]);
      }
}

// -------------------------------------------------------------- proj V ----
// Vt[d][m] = Wv[d][:] . x[m][:] + bv[d]   (fp16 in, bf16 out, transposed)
__global__ __launch_bounds__(256) void proj_v_kernel(
    const unsigned short* __restrict__ wvh, const unsigned short* __restrict__ xh,
    const float* __restrict__ bias, unsigned short* __restrict__ Vt)
{
  __shared__ unsigned short sA[128 * 32], sB[128 * 32];
  const int m0 = blockIdx.y * 128, n0 = blockIdx.x * 128;
  f32x4 acc[4][4];
#pragma unroll
  for (int i = 0; i < 4; ++i)
#pragma unroll
    for (int j = 0; j < 4; ++j) acc[i][j] = (f32x4){0.f, 0.f, 0.f, 0.f};

  gemm_f16_mainloop(wvh + (size_t)m0 * DIM, xh + (size_t)n0 * DIM,
                    DIM, DIM, DIM, sA, sB, acc);
  EPI_SETUP
#pragma unroll
  for (int i = 0; i < 4; ++i)
#pragma unroll
    for (int j = 0; j < 4; ++j)
#pragma unroll
      for (int r = 0; r < 4; ++r) {
        const int row = m0 + wm * 64 + i * 16 + quad * 4 + r;   // d
        const int col = n0 + wn * 64 + j * 16 + fcol;           // seq
        Vt[(size_t)row * MSEQ + col] = f2bf(acc[i][j][r] + bias[row]);
      }
}

// ---------------------------------------------------------------- attn ----
// Fused scores+agg, L2-resident K/V. Block: 32 q-rows x D=512, 512 thr/8 wv.
// Q[32][512] persistent in LDS. Per 128-wide k-tile:
//   phase1 (no barriers): S[32x128] = Q.K^T, K fragments direct from global
//   epilog: P = bf16(adj*exp(S)) -> double-buffered swizzled LDS; den += P
//   ONE barrier (P handoff)
//   phase2 (no barriers): acc[32x512] += P.V^T, V fragments direct from global
// End: shfl butterfly + LDS reduce den -> out = acc/den (nontemporal).
__global__ __launch_bounds__(512, 4) void attn_kernel(
    const unsigned short* __restrict__ Qh, const unsigned short* __restrict__ Kh,
    const unsigned short* __restrict__ Vt, const float* __restrict__ adj,
    float* __restrict__ out)
{
  // LDS 49664B: Qs[32][512] fp16 swizzled (32KB) | Pb[2][32][128] bf16 (16KB)
  //           | denL[4][32] f32 (512B)
  __shared__ __align__(16) unsigned short smem[16384 + 8192 + 256];
  unsigned short* Qs  = smem;                    // row stride 512 ushorts
  unsigned short* Pb0 = smem + 16384;            // row stride 128 ushorts
  float* denL = (float*)(smem + 16384 + 8192);   // [4][32]

  const int tid  = threadIdx.x;
  const int lane = tid & 63;
  const int w    = tid >> 6;                 // 0..7
  const int quad = lane >> 4, fcol = lane & 15;
  const int wq = w >> 2, wk = w & 3;         // phase-1 wave grid 2x4 (16q x 32k)

  // XCD-affinity: round-robin dispatch -> linear%8 = XCD. Put batch b there.
  const int lin = blockIdx.y * gridDim.x + blockIdx.x;   // 0..511
  const int b   = lin & 7;
  const int q0  = (lin >> 3) * QB;
  const size_t qbase = (size_t)b * SEQ + q0;
  const size_t kbb   = (size_t)b * SEQ;
  const float* adjb  = adj + qbase * SEQ;

  // ---- Q tile -> LDS once (pre-swizzled source granules: g' = g ^ (row&7))
#pragma unroll
  for (int c = 0; c < 4; ++c) {
    const int r = w * 4 + c;
    async16(Qh + (qbase + r) * DIM + ((lane ^ (r & 7)) << 3), Qs + r * 512);
  }

  f32x4 acc[2][4];
#pragma unroll
  for (int i = 0; i < 2; ++i)
#pragma unroll
    for (int j = 0; j < 4; ++j) acc[i][j] = (f32x4){0.f, 0.f, 0.f, 0.f};
  float den[4] = {0.f, 0.f, 0.f, 0.f};

  __syncthreads();   // Q ready

  for (int t = 0; t < SEQ / KT; ++t) {
    const int k0 = t * KT;
    unsigned short* Pb = Pb0 + (t & 1) * (32 * 128);

    // ------------- phase 1: S = Q.K^T, K direct from global (L2) --------
    f32x4 sacc[2];
    sacc[0] = (f32x4){0.f, 0.f, 0.f, 0.f};
    sacc[1] = (f32x4){0.f, 0.f, 0.f, 0.f};
    const unsigned short* Kw = Kh + (kbb + k0 + wk * 32) * DIM + quad * 8;
    const int ar = wq * 16 + fcol;
    const size_t aoff = (size_t)ar * 512;
#pragma unroll 4
    for (int kt2 = 0; kt2 < 16; ++kt2) {
      const int kk = kt2 * 32;
      const int gl = kt2 * 4 + quad;
      f16x8 a  = *(const f16x8*)(Qs + aoff + ((gl ^ (ar & 7)) << 3));
      f16x8 b0 = *(const f16x8*)(Kw + (size_t)fcol * DIM + kk);
      f16x8 b1 = *(const f16x8*)(Kw + (size_t)(16 + fcol) * DIM + kk);
      sacc[0] = __builtin_amdgcn_mfma_f32_16x16x32_f16(a, b0, sacc[0], 0, 0, 0);
      sacc[1] = __builtin_amdgcn_mfma_f32_16x16x32_f16(a, b1, sacc[1], 0, 0, 0);
    }

    // --------- epilogue: P = bf16(adj*exp(S)) -> LDS; den += P ----------
#pragma unroll
    for (int j = 0; j < 2; ++j) {
      const int col = wk * 32 + j * 16 + fcol;
#pragma unroll
      for (int r = 0; r < 4; ++r) {
        const int row = wq * 16 + quad * 4 + r;
        const float aval =
            __builtin_nontemporal_load(adjb + (size_t)row * SEQ + k0 + col);
        const unsigned short pb = f2bf(aval * __expf(sacc[j][r]));
        Pb[row * 128 + ((((col >> 3) ^ (row & 7)) << 3) | (col & 7))] = pb;
        den[r] += bf2f(pb);
      }
    }
    __syncthreads();   // P handoff (only barrier in the k-loop)

    // ------------- phase 2: acc += P.V^T, V direct from global (L2) -----
    const unsigned short* Vw = Vt + kbb + k0;
#pragma unroll
    for (int ks = 0; ks < 4; ++ks) {
      const int gl = ks * 4 + quad;
      const int a0r = fcol, a1r = 16 + fcol;
      bf16x8 a0 = *(const bf16x8*)(Pb + a0r * 128 + ((gl ^ (a0r & 7)) << 3));
      bf16x8 a1 = *(const bf16x8*)(Pb + a1r * 128 + ((gl ^ (a1r & 7)) << 3));
#pragma unroll
      for (int j = 0; j < 4; ++j) {
        const int vr = w * 64 + j * 16 + fcol;
        bf16x8 bv = *(const bf16x8*)(Vw + (size_t)vr * MSEQ + ks * 32 + quad * 8);
        acc[0][j] = __builtin_amdgcn_mfma_f32_16x16x32_bf16(a0, bv, acc[0][j], 0, 0, 0);
        acc[1][j] = __builtin_amdgcn_mfma_f32_16x16x32_bf16(a1, bv, acc[1][j], 0, 0, 0);
      }
    }
    // no trailing barrier: Pb double-buffered, next write goes to other half
  }

  // ----------------- den reduce + normalize + store -------------------
#pragma unroll
  for (int r = 0; r < 4; ++r) {
    float v = den[r];
    v += __shfl_xor(v, 1);  v += __shfl_xor(v, 2);
    v += __shfl_xor(v, 4);  v += __shfl_xor(v, 8);
    if (fcol == 0) denL[wk * 32 + wq * 16 + quad * 4 + r] = v;
  }
  __syncthreads();
#pragma unroll
  for (int i = 0; i < 2; ++i)
#pragma unroll
    for (int r = 0; r < 4; ++r) {
      const int row = i * 16 + quad * 4 + r;
      const float d = denL[row] + denL[32 + row] + denL[64 + row] + denL[96 + row];
      const float rd = 1.0f / d;
      float* orow = out + (qbase + row) * DIM + w * 64;
#pragma unroll
      for (int j = 0; j < 4; ++j)
        __builtin_nontemporal_store(acc[i][j][r] * rd, orow + j * 16 + fcol);
    }
}

// -------------------------------------------------------------- launch ----
extern "C" void kernel_launch(void* const* d_in, const int* in_sizes, int n_in,
                              void* d_out, int out_size, void* d_ws, size_t ws_size,
                              hipStream_t stream) {
  const float* x   = (const float*)d_in[0];
  const float* adj = (const float*)d_in[1];
  const float* Wq  = (const float*)d_in[2];
  const float* bq  = (const float*)d_in[3];
  const float* Wk  = (const float*)d_in[4];
  const float* bk  = (const float*)d_in[5];
  const float* Wv  = (const float*)d_in[6];
  const float* bv  = (const float*)d_in[7];
  float* out = (float*)d_out;

  const size_t NX = (size_t)MSEQ * DIM;   // 8,388,608
  const size_t NW = (size_t)DIM * DIM;    // 262,144
  unsigned short* ws = (unsigned short*)d_ws;
  unsigned short* xh  = ws;               // fp16
  unsigned short* wqh = xh + NX;
  unsigned short* wkh = wqh + NW;
  unsigned short* wvh = wkh + NW;
  unsigned short* Qh  = wvh + NW;         // fp16
  unsigned short* Kh  = Qh + NX;          // fp16
  unsigned short* Vt  = Kh + NX;          // bf16, transposed [DIM][MSEQ]

  // 1. fp32 -> fp16 conversions (2 launches)
  cvt_kernel<<<(int)(NX / 4 / 256), 256, 0, stream>>>(x, xh, (int)(NX / 4));
  dim3 cw((int)(NW / 4 / 256), 3);
  cvt_w_kernel<<<cw, 256, 0, stream>>>(Wq, Wk, Wv, wqh, wkh, wvh, (int)(NW / 4));

  // 2. projections (2 launches)
  dim3 pq(DIM / 128, MSEQ / 128, 2);       // (4, 128, 2) — z: Q or K
  proj_qk_kernel<<<pq, 256, 0, stream>>>(xh, wqh, wkh, bq, bk, Qh, Kh);
  dim3 pv(MSEQ / 128, DIM / 128);          // (128, 4)
  proj_v_kernel<<<pv, 256, 0, stream>>>(wvh, xh, bv, Vt);

  // 3. fused attention (scores+agg), L2-resident K/V
  dim3 at(SEQ / QB, BATCH);                // (64, 8) = 512 blocks
  attn_kernel<<<at, 512, 0, stream>>>(Qh, Kh, Vt, adj, out);
}

// Round 5
// 467.073 us; speedup vs baseline: 1.2887x; 1.2887x over previous
//
#include <hip/hip_runtime.h>
#include <hip/hip_bf16.h>

// GraphLayer B=8,N=2048,D=512 — Round 9.
//   r8 post-mortem: compile error only — __builtin_nontemporal_store rejects
//   HIP float4 (class type). This same line was in r7, explaining r7's
//   "container failed twice". Fix: store through native ext-vector f32x4.
//   Architecture unchanged from r8:
//   - Block: 32 q-rows x D=512, 512 thr (8 waves), grid 512 = 2 blocks/CU.
//   - KT=64. Per k-tile: phase1 = 8 chunk-steps (K chunk [64k x 64D] = 8KB,
//     rolling 2x8KB dbuf, stage c+1 while computing c, 1 barrier/step);
//     epilogue P=bf16(adj*exp(S)) -> Pb[32x64]; phase2 = 8 chunk-steps
//     (V chunk [64d x 64k], out^T = MFMA(A=V,B=P)).
//   - All global_load_lds dests wave-uniform (m104); LDS 52.5KB.
//   - XCD affinity lin&7=batch: per-batch K/V (2MB each) stay in one XCD L2.
//   - XOR-granule swizzle on all tiles (pre-swizzled global src + swizzled
//     ds_read, involution); NT adj loads / NT out stores.
// Numerics unchanged vs r4-r6 (absmax 0.0156): fp16 Q/K path, P/V bf16,
// fp32 accum, den = fp32 sum of the SAME bf16-rounded P (cancellation kept).

#define BATCH 8
#define SEQ   2048
#define DIM   512
#define MSEQ  (BATCH * SEQ)   // 16384
#define QB    32              // q-rows per attn block
#define KT    64              // k-tile width
#define NT    (SEQ / KT)      // 32 k-tiles

typedef __attribute__((ext_vector_type(8))) short    bf16x8;
typedef __attribute__((ext_vector_type(8))) _Float16 f16x8;
typedef __attribute__((ext_vector_type(4))) float    f32x4;

__device__ __forceinline__ unsigned short f2bf(float f) {
  __hip_bfloat16 h = __float2bfloat16(f);
  union { __hip_bfloat16 h; unsigned short u; } c; c.h = h; return c.u;
}
__device__ __forceinline__ float bf2f(unsigned short u) {
  union { unsigned int u; float f; } c; c.u = ((unsigned int)u) << 16; return c.f;
}
__device__ __forceinline__ unsigned short f2h(float f) {
  union { _Float16 h; unsigned short u; } c; c.h = (_Float16)f; return c.u;
}

__device__ __forceinline__ void async16(const unsigned short* g, unsigned short* l) {
  __builtin_amdgcn_global_load_lds(
      (const __attribute__((address_space(1))) void*)g,
      (__attribute__((address_space(3))) void*)l, 16, 0, 0);
}

// ---------------------------------------------------------------- core ----
// acc[i][j] += A[m][k] * B[n][k]  (NT), fp16 MFMA, fp32 acc. 256 threads.
// LDS rows 32 ushorts (64B, 4 granules); XOR-swizzled granules (2-way banks).
__device__ __forceinline__ void gemm_f16_mainloop(
    const unsigned short* __restrict__ A, const unsigned short* __restrict__ B,
    int lda, int ldb, int K,
    unsigned short* sA, unsigned short* sB, f32x4 acc[4][4])
{
  const int tid  = threadIdx.x;
  const int lane = tid & 63;
  const int w    = tid >> 6;
  const int wm   = w >> 1, wn = w & 1;
  const int quad = lane >> 4, fcol = lane & 15;
  const int srow = lane >> 2;          // 0..15 within a 16-row chunk
  const int gsw  = ((lane & 3) ^ ((srow & 3) ^ ((srow >> 2) & 3))) * 8;
  const int grd  = ((fcol & 3) ^ ((fcol >> 2) & 3));

  for (int k0 = 0; k0 < K; k0 += 32) {
#pragma unroll
    for (int inst = 0; inst < 2; ++inst) {
      const int rbase  = w * 32 + inst * 16;   // wave-uniform
      const int r      = rbase + srow;
      const int ldsoff = rbase * 32;           // row stride 32 ushorts
      async16(A + (size_t)r * lda + k0 + gsw, sA + ldsoff);
      async16(B + (size_t)r * ldb + k0 + gsw, sB + ldsoff);
    }
    __syncthreads();

#pragma unroll
    for (int i = 0; i < 4; ++i) {
      const int ar = wm * 64 + i * 16 + fcol;
      f16x8 a = *(const f16x8*)(sA + ar * 32 + ((quad ^ grd) << 3));
#pragma unroll
      for (int j = 0; j < 4; ++j) {
        const int br = wn * 64 + j * 16 + fcol;
        f16x8 b = *(const f16x8*)(sB + br * 32 + ((quad ^ grd) << 3));
        acc[i][j] = __builtin_amdgcn_mfma_f32_16x16x32_f16(a, b, acc[i][j], 0, 0, 0);
      }
    }
    __syncthreads();
  }
}

#define EPI_SETUP                                                  \
  const int lane = threadIdx.x & 63;                               \
  const int w_   = threadIdx.x >> 6;                               \
  const int wm   = w_ >> 1, wn = w_ & 1;                           \
  const int quad = lane >> 4, fcol = lane & 15;

// ----------------------------------------------------------------- cvt ----
__global__ __launch_bounds__(256) void cvt_kernel(
    const float* __restrict__ in, unsigned short* __restrict__ out, int n4)
{
  int i = blockIdx.x * 256 + threadIdx.x;
  if (i >= n4) return;
  float4 v = ((const float4*)in)[i];
  ushort4 h;
  h.x = f2h(v.x); h.y = f2h(v.y); h.z = f2h(v.z); h.w = f2h(v.w);
  ((ushort4*)out)[i] = h;
}

__global__ __launch_bounds__(256) void cvt_w_kernel(
    const float* __restrict__ w0, const float* __restrict__ w1,
    const float* __restrict__ w2, unsigned short* __restrict__ o0,
    unsigned short* __restrict__ o1, unsigned short* __restrict__ o2, int n4)
{
  int i = blockIdx.x * 256 + threadIdx.x;
  if (i >= n4) return;
  const float* in = (blockIdx.y == 0) ? w0 : (blockIdx.y == 1) ? w1 : w2;
  unsigned short* out = (blockIdx.y == 0) ? o0 : (blockIdx.y == 1) ? o1 : o2;
  float4 v = ((const float4*)in)[i];
  ushort4 h;
  h.x = f2h(v.x); h.y = f2h(v.y); h.z = f2h(v.z); h.w = f2h(v.w);
  ((ushort4*)out)[i] = h;
}

// ------------------------------------------------------------- proj QK ----
__global__ __launch_bounds__(256) void proj_qk_kernel(
    const unsigned short* __restrict__ xh,
    const unsigned short* __restrict__ wq, const unsigned short* __restrict__ wk,
    const float* __restrict__ bq, const float* __restrict__ bk,
    unsigned short* __restrict__ Qh, unsigned short* __restrict__ Kh)
{
  __shared__ unsigned short sA[128 * 32], sB[128 * 32];
  const unsigned short* wh = blockIdx.z ? wk : wq;
  const float* bias        = blockIdx.z ? bk : bq;
  unsigned short* O        = blockIdx.z ? Kh : Qh;
  const int m0 = blockIdx.y * 128, n0 = blockIdx.x * 128;
  f32x4 acc[4][4];
#pragma unroll
  for (int i = 0; i < 4; ++i)
#pragma unroll
    for (int j = 0; j < 4; ++j) acc[i][j] = (f32x4){0.f, 0.f, 0.f, 0.f};

  gemm_f16_mainloop(xh + (size_t)m0 * DIM, wh + (size_t)n0 * DIM,
                    DIM, DIM, DIM, sA, sB, acc);
  EPI_SETUP
#pragma unroll
  for (int i = 0; i < 4; ++i)
#pragma unroll
    for (int j = 0; j < 4; ++j)
#pragma unroll
      for (int r = 0; r < 4; ++r) {
        const int row = m0 + wm * 64 + i * 16 + quad * 4 + r;
        const int col = n0 + wn * 64 + j * 16 + fcol;
        O[(size_t)row * DIM + col] = f2h(acc[i][j][r] + bias[col]);
      }
}

// -------------------------------------------------------------- proj V ----
// Vt[d][m] = Wv[d][:] . x[m][:] + bv[d]   (fp16 in, bf16 out, transposed)
__global__ __launch_bounds__(256) void proj_v_kernel(
    const unsigned short* __restrict__ wvh, const unsigned short* __restrict__ xh,
    const float* __restrict__ bias, unsigned short* __restrict__ Vt)
{
  __shared__ unsigned short sA[128 * 32], sB[128 * 32];
  const int m0 = blockIdx.y * 128, n0 = blockIdx.x * 128;
  f32x4 acc[4][4];
#pragma unroll
  for (int i = 0; i < 4; ++i)
#pragma unroll
    for (int j = 0; j < 4; ++j) acc[i][j] = (f32x4){0.f, 0.f, 0.f, 0.f};

  gemm_f16_mainloop(wvh + (size_t)m0 * DIM, xh + (size_t)n0 * DIM,
                    DIM, DIM, DIM, sA, sB, acc);
  EPI_SETUP
#pragma unroll
  for (int i = 0; i < 4; ++i)
#pragma unroll
    for (int j = 0; j < 4; ++j)
#pragma unroll
      for (int r = 0; r < 4; ++r) {
        const int row = m0 + wm * 64 + i * 16 + quad * 4 + r;   // d
        const int col = n0 + wn * 64 + j * 16 + fcol;           // seq
        Vt[(size_t)row * MSEQ + col] = f2bf(acc[i][j][r] + bias[row]);
      }
}

// ---------------------------------------------------------------- attn ----
// Fused scores+agg, all-LDS MFMA operands, rolling 2x8KB chunk pipeline.
// Block: 32 q-rows x D=512, 512 threads (8 waves), 2 blocks/CU.
__global__ __launch_bounds__(512, 4) void attn_kernel(
    const unsigned short* __restrict__ Qh, const unsigned short* __restrict__ Kh,
    const unsigned short* __restrict__ Vt, const float* __restrict__ adj,
    float* __restrict__ out)
{
  // LDS 53760B: Qs[32][512] (32KB) | Bf[2][4096] (16KB) | Pb[32][64] (4KB)
  //           | denL[4][32] f32 (512B)
  __shared__ __align__(16) unsigned short smem[26880];
  unsigned short* Qs = smem;                    // row stride 512 ushorts
  unsigned short* Bf = smem + 16384;            // 2 x 4096 ushorts
  unsigned short* Pb = smem + 24576;            // row stride 64 ushorts
  float* denL = (float*)(smem + 26624);         // [4][32]

  const int tid  = threadIdx.x;
  const int lane = tid & 63;
  const int w    = tid >> 6;                    // 0..7
  const int quad = lane >> 4, fcol = lane & 15;
  const int wq = w >> 2, wk = w & 3;            // phase-1 grid 2q x 4k (16x16)
  const int dsub = w >> 1, qsub = w & 1;        // phase-2 grid 4d x 2q (16x16)

  // XCD affinity: round-robin dispatch -> lin%8 = XCD; batch b lives there.
  const int lin = blockIdx.x;                   // 0..511
  const int b   = lin & 7;
  const int q0  = (lin >> 3) * QB;
  const size_t qbase = (size_t)b * SEQ + q0;
  const size_t kbb   = (size_t)b * SEQ;
  const float* adjb  = adj + qbase * SEQ;

  // ---- staging (all LDS bases wave-uniform; per-lane global src swizzled)
  // K chunk: [64 k-rows][64 D] = 8KB, 8 granules/row. Wave w -> rows w*8..+8.
  auto stage_k = [&](int t, int c, int buf) {
    const int row = tid >> 3, g = tid & 7;      // row = w*8 + (lane>>3)
    async16(Kh + (kbb + (size_t)t * KT + row) * DIM + c * 64 + ((g ^ (row & 7)) << 3),
            Bf + buf * 4096 + w * 512);
  };
  // V chunk: [64 d-rows][64 k] = 8KB, 8 granules/row (bf16, Vt row stride MSEQ).
  auto stage_v = [&](int t, int c, int buf) {
    const int row = tid >> 3, g = tid & 7;
    async16(Vt + (size_t)(c * 64 + row) * MSEQ + kbb + (size_t)t * KT + ((g ^ (row & 7)) << 3),
            Bf + buf * 4096 + w * 512);
  };

  // prologue: Q tile [32][512] (once, 4 rounds; wave-uniform dests)
#pragma unroll
  for (int rr = 0; rr < 4; ++rr) {
    const int gp  = rr * 512 + tid;
    const int row = gp >> 6, g = gp & 63;
    async16(Qh + (qbase + row) * DIM + ((g ^ (row & 7)) << 3),
            Qs + (rr * 512 + w * 64) * 8);
  }
  stage_k(0, 0, 0);

  f32x4 acc[8];                                 // out^T: one 16x16 per d-chunk
#pragma unroll
  for (int c = 0; c < 8; ++c) acc[c] = (f32x4){0.f, 0.f, 0.f, 0.f};
  float den[4] = {0.f, 0.f, 0.f, 0.f};

  __syncthreads();   // Q + K0 ready

  for (int t = 0; t < NT; ++t) {
    // ---------------- phase 1: S[32x64] = Q.K^T (8 chunk-steps) ---------
    f32x4 sacc = (f32x4){0.f, 0.f, 0.f, 0.f};
#pragma unroll
    for (int c = 0; c < 8; ++c) {
      if (c < 7) stage_k(t, c + 1, (c + 1) & 1);
      else       stage_v(t, 0, 0);              // prefetch first V chunk
      const unsigned short* Kb = Bf + (c & 1) * 4096;
      const int ar = wq * 16 + fcol;            // q-row
      const int br = wk * 16 + fcol;            // k-row within chunk
#pragma unroll
      for (int ks = 0; ks < 2; ++ks) {
        const int Ga = c * 8 + ks * 4 + quad;   // Q granule (D window)
        const int Gb = ks * 4 + quad;           // K granule within chunk row
        f16x8 a  = *(const f16x8*)(Qs + ar * 512 + ((Ga ^ (ar & 7)) << 3));
        f16x8 bb = *(const f16x8*)(Kb + br * 64 + ((Gb ^ (br & 7)) << 3));
        sacc = __builtin_amdgcn_mfma_f32_16x16x32_f16(a, bb, sacc, 0, 0, 0);
      }
      __syncthreads();
    }

    // --------- epilogue: P = bf16(adj*exp(S)) -> Pb; den += P -----------
    {
      const int col = wk * 16 + fcol;
#pragma unroll
      for (int r = 0; r < 4; ++r) {
        const int row = wq * 16 + quad * 4 + r;
        const float aval =
            __builtin_nontemporal_load(adjb + (size_t)row * SEQ + t * KT + col);
        const unsigned short pb = f2bf(aval * __expf(sacc[r]));
        Pb[row * 64 + ((((col >> 3) ^ (row & 7)) << 3) | (col & 7))] = pb;
        den[r] += bf2f(pb);
      }
    }
    __syncthreads();   // P handoff (V0 already landed)

    // ------------- phase 2: accT[512x32] += V.P^T (8 chunk-steps) -------
#pragma unroll
    for (int c = 0; c < 8; ++c) {
      if (c < 7)            stage_v(t, c + 1, (c + 1) & 1);
      else if (t < NT - 1)  stage_k(t + 1, 0, 0);   // next tile's K0
      const unsigned short* Vb = Bf + (c & 1) * 4096;
      const int dr = dsub * 16 + fcol;          // d-row within chunk
      const int qr = qsub * 16 + fcol;          // q-row
#pragma unroll
      for (int ks = 0; ks < 2; ++ks) {
        const int G = ks * 4 + quad;
        bf16x8 va = *(const bf16x8*)(Vb + dr * 64 + ((G ^ (dr & 7)) << 3));
        bf16x8 pa = *(const bf16x8*)(Pb + qr * 64 + ((G ^ (qr & 7)) << 3));
        acc[c] = __builtin_amdgcn_mfma_f32_16x16x32_bf16(va, pa, acc[c], 0, 0, 0);
      }
      __syncthreads();
    }
  }

  // ----------------- den reduce + normalize + store -------------------
#pragma unroll
  for (int r = 0; r < 4; ++r) {
    float v = den[r];
    v += __shfl_xor(v, 1);  v += __shfl_xor(v, 2);
    v += __shfl_xor(v, 4);  v += __shfl_xor(v, 8);
    if (fcol == 0) denL[wk * 32 + wq * 16 + quad * 4 + r] = v;
  }
  __syncthreads();
  const int qloc = qsub * 16 + fcol;
  const float dsum = denL[qloc] + denL[32 + qloc] + denL[64 + qloc] + denL[96 + qloc];
  const float rd = 1.0f / dsum;
  float* orow = out + (qbase + qloc) * DIM + dsub * 16 + quad * 4;
#pragma unroll
  for (int c = 0; c < 8; ++c) {
    f32x4 o = {acc[c][0] * rd, acc[c][1] * rd, acc[c][2] * rd, acc[c][3] * rd};
    __builtin_nontemporal_store(o, (f32x4*)(orow + c * 64));
  }
}

// -------------------------------------------------------------- launch ----
extern "C" void kernel_launch(void* const* d_in, const int* in_sizes, int n_in,
                              void* d_out, int out_size, void* d_ws, size_t ws_size,
                              hipStream_t stream) {
  const float* x   = (const float*)d_in[0];
  const float* adj = (const float*)d_in[1];
  const float* Wq  = (const float*)d_in[2];
  const float* bq  = (const float*)d_in[3];
  const float* Wk  = (const float*)d_in[4];
  const float* bk  = (const float*)d_in[5];
  const float* Wv  = (const float*)d_in[6];
  const float* bv  = (const float*)d_in[7];
  float* out = (float*)d_out;

  const size_t NX = (size_t)MSEQ * DIM;   // 8,388,608
  const size_t NW = (size_t)DIM * DIM;    // 262,144
  unsigned short* ws = (unsigned short*)d_ws;
  unsigned short* xh  = ws;               // fp16
  unsigned short* wqh = xh + NX;
  unsigned short* wkh = wqh + NW;
  unsigned short* wvh = wkh + NW;
  unsigned short* Qh  = wvh + NW;         // fp16
  unsigned short* Kh  = Qh + NX;          // fp16
  unsigned short* Vt  = Kh + NX;          // bf16, transposed [DIM][MSEQ]

  // 1. fp32 -> fp16 conversions (2 launches)
  cvt_kernel<<<(int)(NX / 4 / 256), 256, 0, stream>>>(x, xh, (int)(NX / 4));
  dim3 cw((int)(NW / 4 / 256), 3);
  cvt_w_kernel<<<cw, 256, 0, stream>>>(Wq, Wk, Wv, wqh, wkh, wvh, (int)(NW / 4));

  // 2. projections (2 launches)
  dim3 pq(DIM / 128, MSEQ / 128, 2);       // (4, 128, 2) — z: Q or K
  proj_qk_kernel<<<pq, 256, 0, stream>>>(xh, wqh, wkh, bq, bk, Qh, Kh);
  dim3 pv(MSEQ / 128, DIM / 128);          // (128, 4)
  proj_v_kernel<<<pv, 256, 0, stream>>>(wvh, xh, bv, Vt);

  // 3. fused attention (scores+agg), all-LDS operands, 2 blocks/CU
  attn_kernel<<<512, 512, 0, stream>>>(Qh, Kh, Vt, adj, out);
}

// Round 7
// 452.786 us; speedup vs baseline: 1.3294x; 1.0316x over previous
//
#include <hip/hip_runtime.h>
#include <hip/hip_bf16.h>

// GraphLayer B=8,N=2048,D=512 — Round 11.
//   r10 post-mortem: FAILED correctness (absmax 0.42). Root cause: raw
//   s_barrier is NOT a compiler memory fence (IntrNoMem) — the ds_reads of
//   chunk c (and the pa reads of Pb) could be HOISTED ABOVE the barrier,
//   reading rows other waves hadn't staged yet. vmcnt(2) only ordered the
//   wave's OWN stage. (Acquire-side analog of guide rule #18.)
//   Fix (sync-only; operand math identical to r9 which passed):
//   - BAR_ACQ(): s_barrier + empty mem-clobber asm + sched_barrier(0) —
//     post-barrier LDS reads cannot hoist above the barrier.
//   - Pre-barrier wait: vmcnt(2) AND lgkmcnt(0) (closes the WAR window;
//     lgkmcnt(0) does not drain the global_load_lds queue per m201).
//   Architecture (r10): counted-vmcnt depth-2 pipeline, 4 rotating 8KB
//   buffers; Q in registers (qf[16]); pa cached once/tile; XCD affinity;
//   grid 512 = 2 blocks/CU; LDS 36.5KB.
// Numerics identical to r9 (passed, absmax 0.0156).

#define BATCH 8
#define SEQ   2048
#define DIM   512
#define MSEQ  (BATCH * SEQ)   // 16384
#define QB    32              // q-rows per attn block
#define KT    64              // k-tile width
#define NTI   (SEQ / KT)      // 32 k-tiles

typedef __attribute__((ext_vector_type(8))) short    bf16x8;
typedef __attribute__((ext_vector_type(8))) _Float16 f16x8;
typedef __attribute__((ext_vector_type(4))) float    f32x4;

__device__ __forceinline__ unsigned short f2bf(float f) {
  __hip_bfloat16 h = __float2bfloat16(f);
  union { __hip_bfloat16 h; unsigned short u; } c; c.h = h; return c.u;
}
__device__ __forceinline__ float bf2f(unsigned short u) {
  union { unsigned int u; float f; } c; c.u = ((unsigned int)u) << 16; return c.f;
}
__device__ __forceinline__ unsigned short f2h(float f) {
  union { _Float16 h; unsigned short u; } c; c.h = (_Float16)f; return c.u;
}

__device__ __forceinline__ void async16(const unsigned short* g, unsigned short* l) {
  __builtin_amdgcn_global_load_lds(
      (const __attribute__((address_space(1))) void*)g,
      (__attribute__((address_space(3))) void*)l, 16, 0, 0);
}

// my stage(c) landed (2 newest stay in flight) + my ds ops complete
#define WAIT_STAGE() \
  asm volatile("s_waitcnt vmcnt(2) lgkmcnt(0)" ::: "memory")
// my P/ds writes committed
#define WAIT_LDS() \
  asm volatile("s_waitcnt lgkmcnt(0)" ::: "memory")
// barrier with ACQUIRE fence: post-barrier LDS reads cannot hoist above
#define BAR_ACQ()                                                  \
  do {                                                             \
    __builtin_amdgcn_s_barrier();                                  \
    asm volatile("" ::: "memory");                                 \
    __builtin_amdgcn_sched_barrier(0);                             \
  } while (0)

// ---------------------------------------------------------------- core ----
// acc[i][j] += A[m][k] * B[n][k]  (NT), fp16 MFMA, fp32 acc. 256 threads.
__device__ __forceinline__ void gemm_f16_mainloop(
    const unsigned short* __restrict__ A, const unsigned short* __restrict__ B,
    int lda, int ldb, int K,
    unsigned short* sA, unsigned short* sB, f32x4 acc[4][4])
{
  const int tid  = threadIdx.x;
  const int lane = tid & 63;
  const int w    = tid >> 6;
  const int wm   = w >> 1, wn = w & 1;
  const int quad = lane >> 4, fcol = lane & 15;
  const int srow = lane >> 2;          // 0..15 within a 16-row chunk
  const int gsw  = ((lane & 3) ^ ((srow & 3) ^ ((srow >> 2) & 3))) * 8;
  const int grd  = ((fcol & 3) ^ ((fcol >> 2) & 3));

  for (int k0 = 0; k0 < K; k0 += 32) {
#pragma unroll
    for (int inst = 0; inst < 2; ++inst) {
      const int rbase  = w * 32 + inst * 16;   // wave-uniform
      const int r      = rbase + srow;
      const int ldsoff = rbase * 32;           // row stride 32 ushorts
      async16(A + (size_t)r * lda + k0 + gsw, sA + ldsoff);
      async16(B + (size_t)r * ldb + k0 + gsw, sB + ldsoff);
    }
    __syncthreads();

#pragma unroll
    for (int i = 0; i < 4; ++i) {
      const int ar = wm * 64 + i * 16 + fcol;
      f16x8 a = *(const f16x8*)(sA + ar * 32 + ((quad ^ grd) << 3));
#pragma unroll
      for (int j = 0; j < 4; ++j) {
        const int br = wn * 64 + j * 16 + fcol;
        f16x8 b = *(const f16x8*)(sB + br * 32 + ((quad ^ grd) << 3));
        acc[i][j] = __builtin_amdgcn_mfma_f32_16x16x32_f16(a, b, acc[i][j], 0, 0, 0);
      }
    }
    __syncthreads();
  }
}

#define EPI_SETUP                                                  \
  const int lane = threadIdx.x & 63;                               \
  const int w_   = threadIdx.x >> 6;                               \
  const int wm   = w_ >> 1, wn = w_ & 1;                           \
  const int quad = lane >> 4, fcol = lane & 15;

// ----------------------------------------------------------------- cvt ----
__global__ __launch_bounds__(256) void cvt_kernel(
    const float* __restrict__ in, unsigned short* __restrict__ out, int n4)
{
  int i = blockIdx.x * 256 + threadIdx.x;
  if (i >= n4) return;
  float4 v = ((const float4*)in)[i];
  ushort4 h;
  h.x = f2h(v.x); h.y = f2h(v.y); h.z = f2h(v.z); h.w = f2h(v.w);
  ((ushort4*)out)[i] = h;
}

__global__ __launch_bounds__(256) void cvt_w_kernel(
    const float* __restrict__ w0, const float* __restrict__ w1,
    const float* __restrict__ w2, unsigned short* __restrict__ o0,
    unsigned short* __restrict__ o1, unsigned short* __restrict__ o2, int n4)
{
  int i = blockIdx.x * 256 + threadIdx.x;
  if (i >= n4) return;
  const float* in = (blockIdx.y == 0) ? w0 : (blockIdx.y == 1) ? w1 : w2;
  unsigned short* out = (blockIdx.y == 0) ? o0 : (blockIdx.y == 1) ? o1 : o2;
  float4 v = ((const float4*)in)[i];
  ushort4 h;
  h.x = f2h(v.x); h.y = f2h(v.y); h.z = f2h(v.z); h.w = f2h(v.w);
  ((ushort4*)out)[i] = h;
}

// ------------------------------------------------------------- proj QK ----
__global__ __launch_bounds__(256) void proj_qk_kernel(
    const unsigned short* __restrict__ xh,
    const unsigned short* __restrict__ wq, const unsigned short* __restrict__ wk,
    const float* __restrict__ bq, const float* __restrict__ bk,
    unsigned short* __restrict__ Qh, unsigned short* __restrict__ Kh)
{
  __shared__ unsigned short sA[128 * 32], sB[128 * 32];
  const unsigned short* wh = blockIdx.z ? wk : wq;
  const float* bias        = blockIdx.z ? bk : bq;
  unsigned short* O        = blockIdx.z ? Kh : Qh;
  const int m0 = blockIdx.y * 128, n0 = blockIdx.x * 128;
  f32x4 acc[4][4];
#pragma unroll
  for (int i = 0; i < 4; ++i)
#pragma unroll
    for (int j = 0; j < 4; ++j) acc[i][j] = (f32x4){0.f, 0.f, 0.f, 0.f};

  gemm_f16_mainloop(xh + (size_t)m0 * DIM, wh + (size_t)n0 * DIM,
                    DIM, DIM, DIM, sA, sB, acc);
  EPI_SETUP
#pragma unroll
  for (int i = 0; i < 4; ++i)
#pragma unroll
    for (int j = 0; j < 4; ++j)
#pragma unroll
      for (int r = 0; r < 4; ++r) {
        const int row = m0 + wm * 64 + i * 16 + quad * 4 + r;
        const int col = n0 + wn * 64 + j * 16 + fcol;
        O[(size_t)row * DIM + col] = f2h(acc[i][j][r] + bias[col]);
      }
}

// -------------------------------------------------------------- proj V ----
// Vt[d][m] = Wv[d][:] . x[m][:] + bv[d]   (fp16 in, bf16 out, transposed)
__global__ __launch_bounds__(256) void proj_v_kernel(
    const unsigned short* __restrict__ wvh, const unsigned short* __restrict__ xh,
    const float* __restrict__ bias, unsigned short* __restrict__ Vt)
{
  __shared__ unsigned short sA[128 * 32], sB[128 * 32];
  const int m0 = blockIdx.y * 128, n0 = blockIdx.x * 128;
  f32x4 acc[4][4];
#pragma unroll
  for (int i = 0; i < 4; ++i)
#pragma unroll
    for (int j = 0; j < 4; ++j) acc[i][j] = (f32x4){0.f, 0.f, 0.f, 0.f};

  gemm_f16_mainloop(wvh + (size_t)m0 * DIM, xh + (size_t)n0 * DIM,
                    DIM, DIM, DIM, sA, sB, acc);
  EPI_SETUP
#pragma unroll
  for (int i = 0; i < 4; ++i)
#pragma unroll
    for (int j = 0; j < 4; ++j)
#pragma unroll
      for (int r = 0; r < 4; ++r) {
        const int row = m0 + wm * 64 + i * 16 + quad * 4 + r;   // d
        const int col = n0 + wn * 64 + j * 16 + fcol;           // seq
        Vt[(size_t)row * MSEQ + col] = f2bf(acc[i][j][r] + bias[row]);
      }
}

// ---------------------------------------------------------------- attn ----
// Fused scores+agg; counted-vmcnt chunk pipeline (depth 2, 4 buffers);
// Q in registers; acquire-fenced raw barriers.
// Block: 32 q-rows x D=512, 512 threads (8 waves), 2 blocks/CU.
__global__ __launch_bounds__(512, 4) void attn_kernel(
    const unsigned short* __restrict__ Qh, const unsigned short* __restrict__ Kh,
    const unsigned short* __restrict__ Vt, const float* __restrict__ adj,
    float* __restrict__ out)
{
  // LDS 37376B: Bf[4][4096] (32KB) | Pb[32][64] (4KB) | denL[4][32] f32 (512B)
  __shared__ __align__(16) unsigned short smem[18688];
  unsigned short* Bf = smem;                    // 4 x 4096 ushorts
  unsigned short* Pb = smem + 16384;            // row stride 64 ushorts
  float* denL = (float*)(smem + 18432);         // [4][32]

  const int tid  = threadIdx.x;
  const int lane = tid & 63;
  const int w    = tid >> 6;                    // 0..7
  const int quad = lane >> 4, fcol = lane & 15;
  const int wq = w >> 2, wk = w & 3;            // phase-1 grid 2q x 4k (16x16)
  const int dsub = w >> 1, qsub = w & 1;        // phase-2 grid 4d x 2q (16x16)

  // XCD affinity: round-robin dispatch -> lin%8 = XCD; batch b lives there.
  const int lin = blockIdx.x;                   // 0..511
  const int b   = lin & 7;
  const int q0  = (lin >> 3) * QB;
  const size_t qbase = (size_t)b * SEQ + q0;
  const size_t kbb   = (size_t)b * SEQ;
  const float* adjb  = adj + qbase * SEQ;

  // ---- staging (LDS bases wave-uniform; per-lane global src swizzled)
  auto stage_k = [&](int t, int c, int buf) {
    const int row = tid >> 3, g = tid & 7;      // row = w*8 + (lane>>3)
    async16(Kh + (kbb + (size_t)t * KT + row) * DIM + c * 64 + ((g ^ (row & 7)) << 3),
            Bf + buf * 4096 + w * 512);
  };
  auto stage_v = [&](int t, int c, int buf) {
    const int row = tid >> 3, g = tid & 7;
    async16(Vt + (size_t)(c * 64 + row) * MSEQ + kbb + (size_t)t * KT + ((g ^ (row & 7)) << 3),
            Bf + buf * 4096 + w * 512);
  };

  // ---- Q fragments -> registers (one-time; row = wq*16+fcol, 16 D-slices)
  const int arq = wq * 16 + fcol;
  f16x8 qf[16];
#pragma unroll
  for (int i = 0; i < 16; ++i)
    qf[i] = *(const f16x8*)(Qh + (qbase + arq) * DIM + i * 32 + quad * 8);

  f32x4 acc[8];                                 // out^T: one 16x16 per d-chunk
#pragma unroll
  for (int c = 0; c < 8; ++c) acc[c] = (f32x4){0.f, 0.f, 0.f, 0.f};
  float den[4] = {0.f, 0.f, 0.f, 0.f};

  // prologue: chunks g=0 (K0->buf0), g=1 (K1->buf1) in flight
  stage_k(0, 0, 0);
  stage_k(0, 1, 1);

  const int br = wk * 16 + fcol;                // phase-1 K row
  const int dr = dsub * 16 + fcol;              // phase-2 V d-row
  const int qr = qsub * 16 + fcol;              // phase-2 P q-row

  for (int t = 0; t < NTI; ++t) {
    // -------- phase 1: S[32x64] = Q.K^T (8 steps, pipelined) ------------
    f32x4 sacc = (f32x4){0.f, 0.f, 0.f, 0.f};
#pragma unroll
    for (int c = 0; c < 8; ++c) {
      if (c < 6) stage_k(t, c + 2, (c + 2) & 3);
      else       stage_v(t, c - 6, (c + 2) & 3);   // V0->buf0, V1->buf1
      WAIT_STAGE();        // my chunk c landed; 2 newest stay in flight
      BAR_ACQ();           // everyone's chunk c landed; reads can't hoist
      const unsigned short* Kb = Bf + (c & 3) * 4096;
#pragma unroll
      for (int ks = 0; ks < 2; ++ks) {
        const int Gb = ks * 4 + quad;
        f16x8 bb = *(const f16x8*)(Kb + br * 64 + ((Gb ^ (br & 7)) << 3));
        sacc = __builtin_amdgcn_mfma_f32_16x16x32_f16(qf[2 * c + ks], bb, sacc, 0, 0, 0);
      }
    }

    // -------- epilogue: P = bf16(adj*exp(S)) -> Pb; den += P ------------
    {
      const int col = wk * 16 + fcol;
#pragma unroll
      for (int r = 0; r < 4; ++r) {
        const int row = wq * 16 + quad * 4 + r;
        const float aval =
            __builtin_nontemporal_load(adjb + (size_t)row * SEQ + t * KT + col);
        const unsigned short pb = f2bf(aval * __expf(sacc[r]));
        Pb[row * 64 + ((((col >> 3) ^ (row & 7)) << 3) | (col & 7))] = pb;
        den[r] += bf2f(pb);
      }
    }
    WAIT_LDS();            // my P writes committed
    BAR_ACQ();             // all P writes visible; V0/V1 stay in flight

    // pa-cache: P fragments once per tile (reused across all 8 chunks)
    bf16x8 pa0 = *(const bf16x8*)(Pb + qr * 64 + ((quad ^ (qr & 7)) << 3));
    bf16x8 pa1 = *(const bf16x8*)(Pb + qr * 64 + (((4 + quad) ^ (qr & 7)) << 3));

    // -------- phase 2: accT[512x32] += V.P^T (8 steps, pipelined) -------
#pragma unroll
    for (int c = 0; c < 8; ++c) {
      if (c < 6) stage_v(t, c + 2, (c + 2) & 3);
      else {                                     // next tile's K0/K1 (wrap)
        const int tn = (t + 1 < NTI) ? t + 1 : 0;
        stage_k(tn, c - 6, (c + 2) & 3);
      }
      WAIT_STAGE();
      BAR_ACQ();
      const unsigned short* Vb = Bf + (c & 3) * 4096;
      bf16x8 va0 = *(const bf16x8*)(Vb + dr * 64 + ((quad ^ (dr & 7)) << 3));
      bf16x8 va1 = *(const bf16x8*)(Vb + dr * 64 + (((4 + quad) ^ (dr & 7)) << 3));
      acc[c] = __builtin_amdgcn_mfma_f32_16x16x32_bf16(va0, pa0, acc[c], 0, 0, 0);
      acc[c] = __builtin_amdgcn_mfma_f32_16x16x32_bf16(va1, pa1, acc[c], 0, 0, 0);
    }
  }

  // ----------------- den reduce + normalize + store -------------------
#pragma unroll
  for (int r = 0; r < 4; ++r) {
    float v = den[r];
    v += __shfl_xor(v, 1);  v += __shfl_xor(v, 2);
    v += __shfl_xor(v, 4);  v += __shfl_xor(v, 8);
    if (fcol == 0) denL[wk * 32 + wq * 16 + quad * 4 + r] = v;
  }
  __syncthreads();   // full drain + fence fine at kernel end
  const int qloc = qsub * 16 + fcol;
  const float dsum = denL[qloc] + denL[32 + qloc] + denL[64 + qloc] + denL[96 + qloc];
  const float rd = 1.0f / dsum;
  float* orow = out + (qbase + qloc) * DIM + dsub * 16 + quad * 4;
#pragma unroll
  for (int c = 0; c < 8; ++c) {
    f32x4 o = {acc[c][0] * rd, acc[c][1] * rd, acc[c][2] * rd, acc[c][3] * rd};
    __builtin_nontemporal_store(o, (f32x4*)(orow + c * 64));
  }
}

// -------------------------------------------------------------- launch ----
extern "C" void kernel_launch(void* const* d_in, const int* in_sizes, int n_in,
                              void* d_out, int out_size, void* d_ws, size_t ws_size,
                              hipStream_t stream) {
  const float* x   = (const float*)d_in[0];
  const float* adj = (const float*)d_in[1];
  const float* Wq  = (const float*)d_in[2];
  const float* bq  = (const float*)d_in[3];
  const float* Wk  = (const float*)d_in[4];
  const float* bk  = (const float*)d_in[5];
  const float* Wv  = (const float*)d_in[6];
  const float* bv  = (const float*)d_in[7];
  float* out = (float*)d_out;

  const size_t NX = (size_t)MSEQ * DIM;   // 8,388,608
  const size_t NW = (size_t)DIM * DIM;    // 262,144
  unsigned short* ws = (unsigned short*)d_ws;
  unsigned short* xh  = ws;               // fp16
  unsigned short* wqh = xh + NX;
  unsigned short* wkh = wqh + NW;
  unsigned short* wvh = wkh + NW;
  unsigned short* Qh  = wvh + NW;         // fp16
  unsigned short* Kh  = Qh + NX;          // fp16
  unsigned short* Vt  = Kh + NX;          // bf16, transposed [DIM][MSEQ]

  // 1. fp32 -> fp16 conversions (2 launches)
  cvt_kernel<<<(int)(NX / 4 / 256), 256, 0, stream>>>(x, xh, (int)(NX / 4));
  dim3 cw((int)(NW / 4 / 256), 3);
  cvt_w_kernel<<<cw, 256, 0, stream>>>(Wq, Wk, Wv, wqh, wkh, wvh, (int)(NW / 4));

  // 2. projections (2 launches)
  dim3 pq(DIM / 128, MSEQ / 128, 2);       // (4, 128, 2) — z: Q or K
  proj_qk_kernel<<<pq, 256, 0, stream>>>(xh, wqh, wkh, bq, bk, Qh, Kh);
  dim3 pv(MSEQ / 128, DIM / 128);          // (128, 4)
  proj_v_kernel<<<pv, 256, 0, stream>>>(wvh, xh, bv, Vt);

  // 3. fused attention (scores+agg), counted-vmcnt pipeline, 2 blocks/CU
  attn_kernel<<<512, 512, 0, stream>>>(Qh, Kh, Vt, adj, out);
}